// Round 1
// 397.171 us; speedup vs baseline: 1.3330x; 1.3330x over previous
//
#include <hip/hip_runtime.h>

// InterpretableMultiHeadAttention  B=1, S=384, D=512, H=8, DK=64
// fp32 in/out (R1/R3 findings from prior session).
//
// Factored algebra (exact):
//   scores_h = 0.125*(q_h (Wq_h Wk_h^T) k_h^T + q_h.uq + k_h.uk + c)
//   hvo_h    = v_h (Wv_s Wo / 8) + pb
//   out[s,t,:] = sum_h attn[h,s,t]*hvo[h,t,:] + bo
//
// R4 (this round): 12 dispatches -> 5. All mutually-independent stages fused
// into block-range mega-kernels so the serialized K=512 GEMMs (pcM/pcP/qkv,
// each <1 block/CU = latency-exposed) run concurrently; attn[7] copy folded
// into softmax; epilogue rewritten float4 + nontemporal stores, no LDS for hv.

#define SS_ 384
#define DD_ 512
#define HH_ 8
#define DKK_ 64

typedef float f32x4 __attribute__((ext_vector_type(4)));

// ---- generic 64x64-tile fp32 GEMM, K multiple of 64, 256 threads ----------
// C[m0+m, n0+n] = scale*(sum_k A[m,k]*B[k,n] + rvec[m] + zvec[n]) + bias[n]
// NT=true: B accessed as B[n, k] (row-major [N,K]).
// LDS passed in so multiple instantiations in one kernel share one allocation.
template <bool NT>
__device__ __forceinline__ void tile64(
    float (* __restrict__ As)[65], float (* __restrict__ Bs)[65],
    const float* __restrict__ A, int lda,
    const float* __restrict__ B, int ldb,
    const float* __restrict__ bias,
    const float* __restrict__ rvec,
    const float* __restrict__ zvec,
    float scale,
    float* __restrict__ C, int ldc, int K, int m0, int n0)
{
    const int tid = threadIdx.x;
    const int lr = tid >> 2;           // 0..63
    const int lc = (tid & 3) << 4;     // 0,16,32,48
    const int ty = tid >> 4, tx = tid & 15;
    float acc[4][4] = {};

    for (int k0 = 0; k0 < K; k0 += 64) {
        const float* Ap = A + (size_t)(m0 + lr) * lda + (k0 + lc);
#pragma unroll
        for (int u = 0; u < 16; u += 4) {
            float4 t4 = *(const float4*)(Ap + u);
            As[lr][lc + u + 0] = t4.x; As[lr][lc + u + 1] = t4.y;
            As[lr][lc + u + 2] = t4.z; As[lr][lc + u + 3] = t4.w;
        }
        if (!NT) {
            const float* Bp = B + (size_t)(k0 + lr) * ldb + (n0 + lc);
#pragma unroll
            for (int u = 0; u < 16; u += 4) {
                float4 t4 = *(const float4*)(Bp + u);
                Bs[lr][lc + u + 0] = t4.x; Bs[lr][lc + u + 1] = t4.y;
                Bs[lr][lc + u + 2] = t4.z; Bs[lr][lc + u + 3] = t4.w;
            }
        } else {
            const float* Bp = B + (size_t)(n0 + lr) * ldb + (k0 + lc);
#pragma unroll
            for (int u = 0; u < 16; ++u) Bs[lc + u][lr] = Bp[u];
        }
        __syncthreads();
#pragma unroll 16
        for (int kk = 0; kk < 64; ++kk) {
            float a[4], b[4];
#pragma unroll
            for (int i = 0; i < 4; ++i) a[i] = As[(ty << 2) + i][kk];
#pragma unroll
            for (int j = 0; j < 4; ++j) b[j] = Bs[kk][(tx << 2) + j];
#pragma unroll
            for (int i = 0; i < 4; ++i)
#pragma unroll
                for (int j = 0; j < 4; ++j)
                    acc[i][j] = fmaf(a[i], b[j], acc[i][j]);
        }
        __syncthreads();
    }
#pragma unroll
    for (int i = 0; i < 4; ++i) {
        const int m = m0 + (ty << 2) + i;
#pragma unroll
        for (int j = 0; j < 4; ++j) {
            const int n = n0 + (tx << 2) + j;
            float val = acc[i][j];
            if (rvec) val += rvec[m];
            if (zvec) val += zvec[n];
            val *= scale;
            if (bias) val += bias[n];
            C[(size_t)m * ldc + n] = val;
        }
    }
}

// ---- stage1: all input-only work, fused --------------------------------
// blocks 0..7    : M_h = Wq_h @ Wk_h^T
// blocks 8..12   : uq/uk/cc dot products
// blocks 13..20  : P = (Wv_s @ Wo)/8
// blocks 21..22  : pb = (bv_s . Wo[:,e])/8
// blocks 23..166 : q/k/v = x @ W + b
__global__ __launch_bounds__(256) void stage1_kernel(
    const float* __restrict__ x,
    const float* __restrict__ Wq, const float* __restrict__ bq,
    const float* __restrict__ Wk, const float* __restrict__ bk,
    const float* __restrict__ Wv, const float* __restrict__ bv,
    const float* __restrict__ Wq_h, const float* __restrict__ bq_h,
    const float* __restrict__ Wk_h, const float* __restrict__ bk_h,
    const float* __restrict__ Wv_s, const float* __restrict__ bv_s,
    const float* __restrict__ Wo,
    float* __restrict__ q, float* __restrict__ k, float* __restrict__ v,
    float* __restrict__ M, float* __restrict__ uq, float* __restrict__ uk,
    float* __restrict__ cc, float* __restrict__ P, float* __restrict__ pb)
{
    __shared__ float As[64][65];
    __shared__ float Bs[64][65];
    const int b = blockIdx.x;
    if (b < 8) {
        const int h = b;
        tile64<true>(As, Bs,
                     Wq_h + (size_t)h * DKK_ * DD_, DD_,
                     Wk_h + (size_t)h * DKK_ * DD_, DD_,
                     nullptr, nullptr, nullptr, 1.0f,
                     M + (size_t)h * DKK_ * DKK_, DKK_, DD_, 0, 0);
    } else if (b < 13) {
        const int id = (b - 8) * 256 + threadIdx.x;
        if (id < 512) {
            const int h = id >> 6, i = id & 63;
            float s = 0.f;
            for (int d = 0; d < DD_; ++d)
                s = fmaf(Wq_h[(size_t)(h * DKK_ + i) * DD_ + d], bk_h[h * DD_ + d], s);
            uq[id] = s;
        } else if (id < 1024) {
            const int t2 = id - 512, h = t2 >> 6, j = t2 & 63;
            float s = 0.f;
            for (int d = 0; d < DD_; ++d)
                s = fmaf(Wk_h[(size_t)(h * DKK_ + j) * DD_ + d], bq_h[h * DD_ + d], s);
            uk[t2] = s;
        } else if (id < 1032) {
            const int h = id - 1024;
            float s = 0.f;
            for (int d = 0; d < DD_; ++d)
                s = fmaf(bq_h[h * DD_ + d], bk_h[h * DD_ + d], s);
            cc[h] = s;
        }
    } else if (b < 21) {
        tile64<false>(As, Bs, Wv_s, DD_, Wo, DD_, nullptr, nullptr, nullptr,
                      0.125f, P, DD_, DD_, 0, (b - 13) * 64);
    } else if (b < 23) {
        const int e = (b - 21) * 256 + threadIdx.x;
        if (e < DD_) {
            float s = 0.f;
            for (int d = 0; d < DD_; ++d)
                s = fmaf(bv_s[d], Wo[(size_t)d * DD_ + e], s);
            pb[e] = 0.125f * s;
        }
    } else {
        const int id = b - 23;                 // 0..143
        const int z = id / 48;                 // q/k/v select
        const int rem = id % 48;
        const int my = rem >> 3, nx = rem & 7;
        const float *W, *bias; float* C;
        if (z == 0)      { W = Wq; bias = bq; C = q; }
        else if (z == 1) { W = Wk; bias = bk; C = k; }
        else             { W = Wv; bias = bv; C = v; }
        tile64<false>(As, Bs, x, DD_, W, DD_, bias, nullptr, nullptr, 1.0f,
                      C, DD_, DD_, my * 64, nx * 64);
    }
}

// ---- stage2: everything depending only on stage1, fused ----------------
// blocks 0..47   : N[h] = q_h @ M_h           (6 m-tiles x 8 heads)
// blocks 48..71  : r[h,s], z[h,t] dot products
// blocks 72..455 : hvo[h] = v_h @ P + pb      (8 n-tiles x 6 m-tiles x 8 heads)
__global__ __launch_bounds__(256) void stage2_kernel(
    const float* __restrict__ q, const float* __restrict__ k,
    const float* __restrict__ v,
    const float* __restrict__ M, const float* __restrict__ uq,
    const float* __restrict__ uk, const float* __restrict__ cc,
    const float* __restrict__ P, const float* __restrict__ pb,
    float* __restrict__ N, float* __restrict__ r, float* __restrict__ z,
    float* __restrict__ hvo)
{
    __shared__ float As[64][65];
    __shared__ float Bs[64][65];
    const int b = blockIdx.x;
    if (b < 48) {
        const int h = b / 6, mx = b % 6;
        tile64<false>(As, Bs, q + h * DKK_, DD_,
                      M + (size_t)h * DKK_ * DKK_, DKK_,
                      nullptr, nullptr, nullptr, 1.0f,
                      N + (size_t)h * SS_ * DKK_, DKK_, DKK_, mx * 64, 0);
    } else if (b < 72) {
        const int id = (b - 48) * 256 + threadIdx.x;
        if (id < HH_ * SS_) {
            const int h = id / SS_, s = id % SS_;
            float acc = cc[h];
            for (int i = 0; i < DKK_; ++i)
                acc = fmaf(q[(size_t)s * DD_ + h * DKK_ + i], uq[h * DKK_ + i], acc);
            r[id] = acc;
        } else if (id < 2 * HH_ * SS_) {
            const int t2 = id - HH_ * SS_;
            const int h = t2 / SS_, t = t2 % SS_;
            float acc = 0.f;
            for (int j = 0; j < DKK_; ++j)
                acc = fmaf(k[(size_t)t * DD_ + h * DKK_ + j], uk[h * DKK_ + j], acc);
            z[t2] = acc;
        }
    } else {
        const int id = b - 72;                 // 0..383
        const int nx = id & 7;
        const int my = (id >> 3) % 6;
        const int h = id / 48;
        tile64<false>(As, Bs, v + h * DKK_, DD_, P, DD_, pb, nullptr, nullptr,
                      1.0f, hvo + (size_t)h * SS_ * DD_, DD_, DKK_,
                      my * 64, nx * 64);
    }
}

// ---- attn_pre[h] = 0.125*(N_h @ k_h^T + r + z)   (grid 6,6,8) --------------
__global__ __launch_bounds__(256) void scores_kernel(
    const float* __restrict__ N, const float* __restrict__ k,
    const float* __restrict__ r, const float* __restrict__ z,
    float* __restrict__ attn)
{
    __shared__ float As[64][65];
    __shared__ float Bs[64][65];
    const int h = blockIdx.z;
    tile64<true>(As, Bs,
                 N + (size_t)h * SS_ * DKK_, DKK_,
                 k + h * DKK_, DD_,
                 nullptr, r + h * SS_, z + h * SS_, 0.125f,
                 attn + (size_t)h * SS_ * SS_, SS_, DKK_,
                 blockIdx.y * 64, blockIdx.x * 64);
}

// ---- row softmax over t, in place; h==7 rows also copied to out1 ----------
__global__ __launch_bounds__(512) void softmax_kernel(
    float* __restrict__ attn, float* __restrict__ out2)
{
    __shared__ float red[512];
    float* p = attn + (size_t)blockIdx.x * SS_;
    const int tid = threadIdx.x;
    const float x = (tid < SS_) ? p[tid] : -INFINITY;
    red[tid] = x;
    __syncthreads();
    for (int st = 256; st > 0; st >>= 1) {
        if (tid < st) red[tid] = fmaxf(red[tid], red[tid + st]);
        __syncthreads();
    }
    const float m = red[0];
    __syncthreads();
    const float e = (tid < SS_) ? __expf(x - m) : 0.0f;
    red[tid] = e;
    __syncthreads();
    for (int st = 256; st > 0; st >>= 1) {
        if (tid < st) red[tid] += red[tid + st];
        __syncthreads();
    }
    const float inv = 1.0f / red[0];
    if (tid < SS_) {
        const float val = e * inv;
        p[tid] = val;
        const int row7 = blockIdx.x - 7 * SS_;
        if (row7 >= 0) out2[(size_t)row7 * SS_ + tid] = val;
    }
}

// ---- out[s,t,:] = sum_h attn[h,s,t]*hvo[h,t,:] + bo   (grid 384,12) --------
// float4 lanes (16B/lane stores), hv in registers, nontemporal output stores
// (302 MB write-once: keep it out of L2 so hvo stays resident).
__global__ __launch_bounds__(256) void epilogue_kernel(
    const float* __restrict__ attn, const float* __restrict__ hvo,
    const float* __restrict__ bo, float* __restrict__ out)
{
    __shared__ float aT[HH_][32];
    const int t = blockIdx.x;
    const int s0 = blockIdx.y * 32;
    const int tid = threadIdx.x;

    {
        const int h = tid >> 5, si = tid & 31;
        aT[h][si] = attn[(size_t)h * SS_ * SS_ + (size_t)(s0 + si) * SS_ + t];
    }
    const int dq = (tid & 127) << 2;   // 0..508 step 4
    const int sh = tid >> 7;           // 0..1: which si parity this half handles
    f32x4 hv[HH_];
#pragma unroll
    for (int h = 0; h < HH_; ++h)
        hv[h] = *(const f32x4*)(hvo + ((size_t)h * SS_ + t) * DD_ + dq);
    const f32x4 b4 = *(const f32x4*)(bo + dq);
    __syncthreads();

#pragma unroll
    for (int i = 0; i < 16; ++i) {
        const int si = sh + (i << 1);
        f32x4 o = b4;
#pragma unroll
        for (int h = 0; h < HH_; ++h) {
            const float a = aT[h][si];
            o.x = fmaf(a, hv[h].x, o.x);
            o.y = fmaf(a, hv[h].y, o.y);
            o.z = fmaf(a, hv[h].z, o.z);
            o.w = fmaf(a, hv[h].w, o.w);
        }
        float* p = out + ((size_t)(s0 + si) * SS_ + t) * DD_ + dq;
        __builtin_nontemporal_store(o, (f32x4*)p);
    }
}

extern "C" void kernel_launch(void* const* d_in, const int* in_sizes, int n_in,
                              void* d_out, int out_size, void* d_ws, size_t ws_size,
                              hipStream_t stream) {
    const float* x    = (const float*)d_in[0];
    const float* Wq   = (const float*)d_in[1];
    const float* bq   = (const float*)d_in[2];
    const float* Wk   = (const float*)d_in[3];
    const float* bk   = (const float*)d_in[4];
    const float* Wv   = (const float*)d_in[5];
    const float* bv   = (const float*)d_in[6];
    const float* Wq_h = (const float*)d_in[7];
    const float* bq_h = (const float*)d_in[8];
    const float* Wk_h = (const float*)d_in[9];
    const float* bk_h = (const float*)d_in[10];
    const float* Wv_s = (const float*)d_in[11];
    const float* bv_s = (const float*)d_in[12];
    const float* Wo   = (const float*)d_in[13];
    const float* bo   = (const float*)d_in[14];

    const size_t SD  = (size_t)SS_ * DD_;    // 196608
    const size_t SSZ = (size_t)SS_ * SS_;    // 147456
    float* ws = (float*)d_ws;
    float* q    = ws;               ws += SD;
    float* k    = ws;               ws += SD;
    float* v    = ws;               ws += SD;
    float* M    = ws;               ws += (size_t)HH_ * DKK_ * DKK_;  // 32768
    float* uq   = ws;               ws += HH_ * DKK_;                 // 512
    float* uk   = ws;               ws += HH_ * DKK_;                 // 512
    float* cc   = ws;               ws += 32;                         // 8 (padded)
    float* N    = ws;               ws += (size_t)HH_ * SS_ * DKK_;   // 196608
    float* r    = ws;               ws += HH_ * SS_;                  // 3072
    float* z    = ws;               ws += HH_ * SS_;                  // 3072
    float* P    = ws;               ws += (size_t)DKK_ * DD_;         // 32768
    float* pb   = ws;               ws += DD_;                        // 512
    float* attn = ws;               ws += (size_t)HH_ * SSZ;          // 1179648
    float* hvo  = ws;               ws += (size_t)HH_ * SD;           // 1572864

    float* out0 = (float*)d_out;                   // [1,384,384,512] fp32
    float* out1 = out0 + (size_t)SS_ * SS_ * DD_;  // [1,384,384] fp32

    stage1_kernel<<<dim3(167),        256, 0, stream>>>(
        x, Wq, bq, Wk, bk, Wv, bv, Wq_h, bq_h, Wk_h, bk_h, Wv_s, bv_s, Wo,
        q, k, v, M, uq, uk, cc, P, pb);
    stage2_kernel<<<dim3(456),        256, 0, stream>>>(
        q, k, v, M, uq, uk, cc, P, pb, N, r, z, hvo);
    scores_kernel<<<dim3(6, 6, HH_),  256, 0, stream>>>(N, k, r, z, attn);
    softmax_kernel<<<dim3(HH_ * SS_), 512, 0, stream>>>(attn, out1);
    epilogue_kernel<<<dim3(SS_, 12),  256, 0, stream>>>(attn, hvo, bo, out0);
}